// Round 9
// baseline (121.661 us; speedup 1.0000x reference)
//
#include <hip/hip_runtime.h>
#include <hip/hip_bf16.h>
#include <math.h>

// Problem: B=4, L=2048 (M = 8192 rows), D_MODEL = 768, N_STATE = 16.
// y[row,d] = x[row,d] * softplus((x@W1+b1)[row,d]) * dot(x@W2+b2, x@W3+b3)[row]
// Ledger (timed totals, the only trustworthy metric): R0=112.1 (xb precompute,
// 29KB single-buffer k-loop) | R12/13/15 reg-staged A = -4..-9 (compiler
// sinks or spills) | R16 (2x occ) / R17 (dbuf T3) / R19 (coalesced epilogue)
// all null -> gemm insensitive to sync/occupancy/epilogue at K=768 (12 steps).
// R20 (this round): kill the xb detour WITHOUT registers — stage x fp32
// straight to LDS via async16 (zero-reg, latency structure == R0), convert
// bf16 at fragment-read time (2x ds_read f32x4 -> v_cvt_pk -> MFMA). Prep
// shrinks to W-only (608 blocks, ~1.5us). Epilogue = R19 streaming, x fp32.
// LDS 45KB -> 3 blocks/CU (R16 proved occupancy-insensitive). Pair-granular
// XOR swizzle, pre-swizzled GLOBAL source + linear LDS dest (rule #21).

#define M_ROWS 8192
#define DM 768
#define NS 16

typedef short bf16x8 __attribute__((ext_vector_type(8)));
typedef unsigned short u16x8 __attribute__((ext_vector_type(8)));
typedef float f32x4 __attribute__((ext_vector_type(4)));

__device__ __forceinline__ unsigned short f2bf(float f) {
    union { float f; unsigned u; } v; v.f = f;
    unsigned r = v.u + 0x7FFF + ((v.u >> 16) & 1);   // RNE
    return (unsigned short)(r >> 16);
}
__device__ __forceinline__ void async16(const void* g, void* l) {
    __builtin_amdgcn_global_load_lds(
        (const __attribute__((address_space(1))) void*)g,
        (__attribute__((address_space(3))) void*)l,
        16, 0, 0);
}
// branchless stable softplus: max(v,0) + log(1+exp(-|v|)); HW exp/log.
__device__ __forceinline__ float softplus_fast(float v) {
    return fmaxf(v, 0.f) + __logf(1.f + __expf(-fabsf(v)));
}

// ---- kernel 1: W-prep only (608 blocks) ---------------------------------
// bid [0,32):   w23t build (bf16 n-major, pair-interleaved W2/W3 cols).
// bid [32,608): W1 [k][n] fp32 -> w1t [n][k] bf16 (32x32 LDS tiles).
__global__ __launch_bounds__(256) void prep_kernel(
    const float* __restrict__ W1,
    const float* __restrict__ W2,
    const float* __restrict__ W3,
    unsigned short* __restrict__ w1t,
    unsigned short* __restrict__ w23t)
{
    __shared__ float tile[32][33];
    const int bid = blockIdx.x;
    const int tid = threadIdx.x;
    if (bid < 32) {
        const int n = bid, i = n >> 1;
        const float* src = (n & 1) ? W3 : W2;
        #pragma unroll
        for (int e = 0; e < 3; ++e) {
            int k = e * 256 + tid;
            w23t[n * DM + k] = f2bf(src[k * NS + i]);
        }
    } else {
        const int b2i = bid - 32;                // 0..575
        const int n0 = (b2i % 24) * 32, k0 = (b2i / 24) * 32;
        const int tx = tid & 31, ty = tid >> 5;  // 32 x 8
        #pragma unroll
        for (int i = 0; i < 4; ++i) {
            int k = ty + i * 8;
            tile[k][tx] = W1[(k0 + k) * DM + n0 + tx];
        }
        __syncthreads();
        #pragma unroll
        for (int i = 0; i < 4; ++i) {
            int n = ty + i * 8;
            w1t[(n0 + n) * DM + k0 + tx] = f2bf(tile[tx][n]);
        }
    }
}

// ---- kernel 2: fp32-A k-loop + fused s + streaming epilogue -------------
// R0-exact sync structure (single-buffer, 2 barriers/step, 4 waves 2x2,
// 128x64 tile, XCD swizzle). A staged as fp32 (32 KB/step, 8 async16/thr,
// pair-granular XOR swizzle on the GLOBAL source, linear LDS dest); A
// fragments built at read time: 2x ds_read f32x4 -> 8x RNE cvt (compiler
// emits v_cvt_pk_bf16_f32) -> bf16x8. B/W paths and all verified algebra
// (P-gemm, shfl s-reduction, fragment indices) unchanged from R0.
__global__ __launch_bounds__(256) void gemm_fused_kernel(
    const float* __restrict__ x,              // [8192][768] fp32
    const unsigned short* __restrict__ w1t,   // [768][768] bf16, n-major
    const unsigned short* __restrict__ w23t,  // [32][768] bf16, pair-interleaved
    const float* __restrict__ b1,
    const float* __restrict__ b2, const float* __restrict__ b3,
    float* __restrict__ y)
{
    __shared__ __align__(16) char smem[46080];               // 45 KB
    float*          Alf   = (float*)(smem);                  // 32 KB [128][64] f32
    unsigned short* Bl    = (unsigned short*)(smem + 32768); //  8 KB
    unsigned short* Wl    = (unsigned short*)(smem + 40960); //  4 KB
    float*          spart = (float*)(smem + 45056);          //  1 KB [2][128]
    float*          ytile = (float*)(smem);                  //  8 KB overlays Alf

    const int b = blockIdx.x;
    const int c = b & 7, j = b >> 3;          // j in [0,96)
    const int m0 = (c * 8 + j / 12) * 128;
    const int n0 = (j % 12) * 64;
    const int tid  = threadIdx.x;
    const int lane = tid & 63;
    const int wave = tid >> 6;
    const int wm = wave >> 1, wn = wave & 1;
    const int l15 = lane & 15, quad = lane >> 4;

    f32x4 acc[4][2];
    f32x4 accP[4];
    #pragma unroll
    for (int i = 0; i < 4; ++i) {
        accP[i] = (f32x4){0.f, 0.f, 0.f, 0.f};
        #pragma unroll
        for (int jj = 0; jj < 2; ++jj)
            acc[i][jj] = (f32x4){0.f, 0.f, 0.f, 0.f};
    }

    for (int k0 = 0; k0 < DM; k0 += 64) {
        // A: 2048 16B-chunks of fp32. LDS dest linear in tid (rule #21);
        // global source pair-XOR-preswizzled: chunk (r, cgs) holds global
        // 16B-unit ((cgs>>1)^(r&7))*2 + (cgs&1) of row r's k-slice.
        #pragma unroll
        for (int i = 0; i < 8; ++i) {
            int ch = tid + i * 256;
            int r = ch >> 4, cgs = ch & 15;
            int u16i = (((cgs >> 1) ^ (r & 7)) << 1) | (cgs & 1);  // 0..15
            async16(x + (m0 + r) * DM + k0 + u16i * 4, (char*)Alf + ch * 16);
        }
        #pragma unroll
        for (int i = 0; i < 2; ++i) {         // B: 512 chunks (bf16, as R0)
            int ch = tid + i * 256;
            int r = ch >> 3, jg = (ch & 7) ^ (r & 7);
            async16(w1t + (n0 + r) * DM + k0 + jg * 8, Bl + ch * 8);
        }
        {                                      // W23: 256 chunks
            int ch = tid;
            int r = ch >> 3, jg = (ch & 7) ^ (r & 7);
            async16(w23t + r * DM + k0 + jg * 8, Wl + ch * 8);
        }
        __syncthreads();

        #pragma unroll
        for (int kk = 0; kk < 2; ++kk) {
            bf16x8 bfr[2], wfr;
            #pragma unroll
            for (int jj = 0; jj < 2; ++jj) {
                int rb = wn * 32 + jj * 16 + l15;
                int jb = (kk * 4 + quad) ^ (rb & 7);
                bfr[jj] = *(const bf16x8*)(Bl + rb * 64 + jb * 8);
            }
            {
                int rw = wn * 16 + l15;
                int jw = (kk * 4 + quad) ^ (rw & 7);
                wfr = *(const bf16x8*)(Wl + rw * 64 + jw * 8);
            }
            #pragma unroll
            for (int i = 0; i < 4; ++i) {
                int rr = wm * 64 + i * 16 + l15;
                int kp = kk * 4 + quad;            // 32B-pair index 0..7
                int p  = kp ^ (rr & 7);
                const f32x4* ap = (const f32x4*)(Alf + rr * 64 + p * 8);
                f32x4 a0 = ap[0], a1 = ap[1];
                union { u16x8 h; bf16x8 v; } au;
                au.h[0] = f2bf(a0[0]); au.h[1] = f2bf(a0[1]);
                au.h[2] = f2bf(a0[2]); au.h[3] = f2bf(a0[3]);
                au.h[4] = f2bf(a1[0]); au.h[5] = f2bf(a1[1]);
                au.h[6] = f2bf(a1[2]); au.h[7] = f2bf(a1[3]);
                bf16x8 af = au.v;
                #pragma unroll
                for (int jj = 0; jj < 2; ++jj)
                    acc[i][jj] = __builtin_amdgcn_mfma_f32_16x16x32_bf16(
                        af, bfr[jj], acc[i][jj], 0, 0, 0);
                accP[i] = __builtin_amdgcn_mfma_f32_16x16x32_bf16(
                    af, wfr, accP[i], 0, 0, 0);
            }
        }
        __syncthreads();
    }

    // ---- s partials: this wave owns pairs p = wn*8 + (l15>>1) ----
    {
        const int p = wn * 8 + (l15 >> 1);
        const float bB = b2[p], bC = b3[p];
        #pragma unroll
        for (int i = 0; i < 4; ++i) {
            float sacc[4];
            #pragma unroll
            for (int r = 0; r < 4; ++r) {
                float v = accP[i][r];
                float pv = __shfl_xor(v, 1, 64);
                sacc[r] = (l15 & 1) ? (pv + bB) * (v + bC)
                                    : (v + bB) * (pv + bC);
                sacc[r] += __shfl_xor(sacc[r], 1, 64);
                sacc[r] += __shfl_xor(sacc[r], 2, 64);
                sacc[r] += __shfl_xor(sacc[r], 4, 64);
                sacc[r] += __shfl_xor(sacc[r], 8, 64);
            }
            if (l15 == 0) {
                #pragma unroll
                for (int r = 0; r < 4; ++r)
                    spart[wn * 128 + wm * 64 + i * 16 + quad * 4 + r] = 0.5f * sacc[r];
            }
        }
    }
    __syncthreads();   // also retires all Alf reads before ytile overlay

    // ---- epilogue: LDS bounce -> fully-coalesced streaming IO ----
    // writer: fragment layout computes t = softplus(acc+b1)*sv into
    //   ytile[32][64]; reader: thread owns row tid>>3, cols (tid&7)*8..+8
    //   -> two f32x4 x loads + two f32x4 y stores, all full-line.
    const int row_l = tid >> 3;              // 0..31
    const int cg    = tid & 7;               // 0..7
    const int grow_base = m0 + (row_l >> 4) * 64 + (row_l & 15);
    const int gcol_r    = n0 + cg * 8;
    #pragma unroll
    for (int i = 0; i < 4; ++i) {
        const int rl = wm * 64 + i * 16 + quad * 4;
        float sv4[4];
        #pragma unroll
        for (int r = 0; r < 4; ++r)
            sv4[r] = spart[rl + r] + spart[128 + rl + r];
        #pragma unroll
        for (int jj = 0; jj < 2; ++jj) {
            const int tc = wn * 32 + jj * 16 + l15;
            const float bias = b1[n0 + tc];
            #pragma unroll
            for (int r = 0; r < 4; ++r) {
                float v = acc[i][jj][r] + bias;
                float sp = softplus_fast(v);
                ytile[(wm * 16 + quad * 4 + r) * 64 + tc] = sp * sv4[r];
            }
        }
        __syncthreads();
        const int grow = grow_base + i * 16;
        f32x4 t0 = *(const f32x4*)&ytile[row_l * 64 + cg * 8];
        f32x4 t1 = *(const f32x4*)&ytile[row_l * 64 + cg * 8 + 4];
        f32x4 xv0 = *(const f32x4*)(x + grow * DM + gcol_r);
        f32x4 xv1 = *(const f32x4*)(x + grow * DM + gcol_r + 4);
        f32x4 o0, o1;
        #pragma unroll
        for (int e = 0; e < 4; ++e) {
            o0[e] = t0[e] * xv0[e];
            o1[e] = t1[e] * xv1[e];
        }
        *(f32x4*)(y + grow * DM + gcol_r)     = o0;
        *(f32x4*)(y + grow * DM + gcol_r + 4) = o1;
        if (i < 3) __syncthreads();          // ytile reused next i-tile
    }
}

extern "C" void kernel_launch(void* const* d_in, const int* in_sizes, int n_in,
                              void* d_out, int out_size, void* d_ws, size_t ws_size,
                              hipStream_t stream) {
    const float* x  = (const float*)d_in[0];
    const float* W1 = (const float*)d_in[1];
    const float* b1 = (const float*)d_in[2];
    const float* W2 = (const float*)d_in[3];
    const float* b2 = (const float*)d_in[4];
    const float* W3 = (const float*)d_in[5];
    const float* b3 = (const float*)d_in[6];
    // d_in[7] = A : unused (multiplied by h0 == 0 in the reference)
    float* y = (float*)d_out;

    unsigned short* w1t  = (unsigned short*)d_ws;                     // 1,179,648 B
    unsigned short* w23t = (unsigned short*)((char*)d_ws + 1179648);  //    49,152 B

    prep_kernel<<<608, 256, 0, stream>>>(W1, W2, W3, w1t, w23t);
    gemm_fused_kernel<<<768, 256, 0, stream>>>(x, w1t, w23t, b1, b2, b3, y);
}